// Round 1
// baseline (49.562 us; speedup 1.0000x reference)
//
#include <hip/hip_runtime.h>

// ---- constants matching the reference ----
#define NORMC 27353.34765625f
__device__ __constant__ float kALPHA = 0.0257f;
#define SRC_INTENSITY (100000.0f / NORMC)
#define FIRE_THRESHOLD (980.0f / NORMC)

constexpr int Wd = 128, Hd = 128, Dd = 64, Bd = 16;
constexpr int HW = Hd * Wd;            // 16384
constexpr long long NTOT = (long long)Bd * Dd * Hd * Wd;  // 16777216
constexpr int N4 = (int)(NTOT / 4);    // 4194304
constexpr int NBLOCKS = 2048;
constexpr int NTHREADS = 256;

__global__ __launch_bounds__(NTHREADS) void loss_main(
    const float* __restrict__ in,
    const float* __restrict__ outp_cur,
    const float* __restrict__ outp_past,
    const float* __restrict__ tvec,
    const float* __restrict__ tpvec,
    const float* __restrict__ tgt,
    float2* __restrict__ partial)
{
    const float alpha = kALPHA;
    float sp = 0.0f;   // sum of residual^2
    float sm = 0.0f;   // sum of (out - target)^2

    for (int i4 = blockIdx.x * blockDim.x + threadIdx.x; i4 < N4;
         i4 += gridDim.x * blockDim.x) {
        const int idx = i4 << 2;              // element index of lane's first elem
        const int x0 = idx & (Wd - 1);        // 0,4,...,124
        const int y  = (idx >> 7) & (Hd - 1);
        const int z  = (idx >> 14) & (Dd - 1);
        const int b  = idx >> 20;

        const float4 c = *(const float4*)(in + idx);
        float4 ym = make_float4(0.f, 0.f, 0.f, 0.f);
        float4 yp = make_float4(0.f, 0.f, 0.f, 0.f);
        float4 zm = make_float4(0.f, 0.f, 0.f, 0.f);
        float4 zp = make_float4(0.f, 0.f, 0.f, 0.f);
        if (y > 0)      ym = *(const float4*)(in + idx - Wd);
        if (y < Hd - 1) yp = *(const float4*)(in + idx + Wd);
        if (z > 0)      zm = *(const float4*)(in + idx - HW);
        if (z < Dd - 1) zp = *(const float4*)(in + idx + HW);
        const float xl = (x0 > 0)        ? in[idx - 1] : 0.0f;
        const float xr = (x0 < Wd - 4)   ? in[idx + 4] : 0.0f;

        const float lap0 = xl  + c.y + ym.x + yp.x + zm.x + zp.x - 6.0f * c.x;
        const float lap1 = c.x + c.z + ym.y + yp.y + zm.y + zp.y - 6.0f * c.y;
        const float lap2 = c.y + c.w + ym.z + yp.z + zm.z + zp.z - 6.0f * c.z;
        const float lap3 = c.z + xr  + ym.w + yp.w + zm.w + zp.w - 6.0f * c.w;

        const float dt = tvec[b] - tpvec[b];

        const float4 o  = *(const float4*)(outp_cur + idx);
        const float4 op = *(const float4*)(outp_past + idx);
        const float4 tg = *(const float4*)(tgt + idx);

        const float src0 = (c.x > FIRE_THRESHOLD) ? SRC_INTENSITY : 0.0f;
        const float src1 = (c.y > FIRE_THRESHOLD) ? SRC_INTENSITY : 0.0f;
        const float src2 = (c.z > FIRE_THRESHOLD) ? SRC_INTENSITY : 0.0f;
        const float src3 = (c.w > FIRE_THRESHOLD) ? SRC_INTENSITY : 0.0f;

        const float r0 = (o.x - op.x) / dt - alpha * lap0 - src0;
        const float r1 = (o.y - op.y) / dt - alpha * lap1 - src1;
        const float r2 = (o.z - op.z) / dt - alpha * lap2 - src2;
        const float r3 = (o.w - op.w) / dt - alpha * lap3 - src3;
        sp += r0 * r0 + r1 * r1 + r2 * r2 + r3 * r3;

        const float m0 = o.x - tg.x, m1 = o.y - tg.y;
        const float m2 = o.z - tg.z, m3 = o.w - tg.w;
        sm += m0 * m0 + m1 * m1 + m2 * m2 + m3 * m3;
    }

    // wave reduction (width 64)
    #pragma unroll
    for (int off = 32; off > 0; off >>= 1) {
        sp += __shfl_down(sp, off);
        sm += __shfl_down(sm, off);
    }
    __shared__ float2 wsum[NTHREADS / 64];
    const int lane = threadIdx.x & 63;
    const int wid  = threadIdx.x >> 6;
    if (lane == 0) wsum[wid] = make_float2(sp, sm);
    __syncthreads();
    if (threadIdx.x == 0) {
        float ap = 0.0f, am = 0.0f;
        #pragma unroll
        for (int w = 0; w < NTHREADS / 64; ++w) { ap += wsum[w].x; am += wsum[w].y; }
        partial[blockIdx.x] = make_float2(ap, am);
    }
}

__global__ __launch_bounds__(256) void loss_reduce(
    const float2* __restrict__ partial, float* __restrict__ out)
{
    double sp = 0.0, sm = 0.0;
    for (int i = threadIdx.x; i < NBLOCKS; i += blockDim.x) {
        const float2 v = partial[i];
        sp += (double)v.x;
        sm += (double)v.y;
    }
    #pragma unroll
    for (int off = 32; off > 0; off >>= 1) {
        sp += __shfl_down(sp, off);
        sm += __shfl_down(sm, off);
    }
    __shared__ double wsp[4], wsm[4];
    const int lane = threadIdx.x & 63;
    const int wid  = threadIdx.x >> 6;
    if (lane == 0) { wsp[wid] = sp; wsm[wid] = sm; }
    __syncthreads();
    if (threadIdx.x == 0) {
        double tp = 0.0, tm = 0.0;
        #pragma unroll
        for (int w = 0; w < 4; ++w) { tp += wsp[w]; tm += wsm[w]; }
        const double invN = 1.0 / (double)NTOT;
        out[0] = (float)(tm * invN + tp * invN);   // mse + A * p_loss, A = 1
    }
}

extern "C" void kernel_launch(void* const* d_in, const int* in_sizes, int n_in,
                              void* d_out, int out_size, void* d_ws, size_t ws_size,
                              hipStream_t stream) {
    const float* in_   = (const float*)d_in[0];
    const float* out_  = (const float*)d_in[1];
    const float* outp_ = (const float*)d_in[2];
    const float* t_    = (const float*)d_in[3];
    const float* tp_   = (const float*)d_in[4];
    const float* tgt_  = (const float*)d_in[5];

    float2* partial = (float2*)d_ws;   // needs NBLOCKS * 8 = 16 KiB

    loss_main<<<NBLOCKS, NTHREADS, 0, stream>>>(in_, out_, outp_, t_, tp_, tgt_, partial);
    loss_reduce<<<1, 256, 0, stream>>>(partial, (float*)d_out);
}